// Round 6
// baseline (509.687 us; speedup 1.0000x reference)
//
#include <hip/hip_runtime.h>
#include <stdint.h>

typedef uint16_t u16;
typedef uint32_t u32;
typedef uint64_t u64;
typedef float f32x4 __attribute__((ext_vector_type(4)));
typedef __bf16 bf16x8 __attribute__((ext_vector_type(8)));

#define DEVI __device__ __forceinline__

struct U4 { u32 a, b, c, d; };

DEVI u16 f2bf(float f) {
    u32 u = __builtin_bit_cast(u32, f);
    return (u16)((u + 0x7FFFu + ((u >> 16) & 1u)) >> 16);
}
DEVI float bf2f(u32 h) { return __builtin_bit_cast(float, h << 16); }
DEVI u32 cvt_pk_bf16(float lo, float hi) {
    u32 r;
    asm("v_cvt_pk_bf16_f32 %0, %1, %2" : "=v"(r) : "v"(lo), "v"(hi));
    return r;
}

DEVI float gelu_f(float x) {
    float u = 0.7978845608028654f * (x + 0.044715f * x * x * x);
    float t = exp2f(u * 2.885390081777927f);
    return x * (1.f - 1.f / (t + 1.f));
}

#define GLOAD_LDS16(gp, lp) \
    __builtin_amdgcn_global_load_lds((const __attribute__((address_space(1))) void*)(gp), \
                                     (__attribute__((address_space(3))) void*)(lp), 16, 0, 0)

// ---------------- fused weight transposes fp32[K][N] -> bf16[N][K] ----------------
struct WtJobs {
    const float* src[4]; u16* dst[4];
    int K[4], N[4], ntx[4], start[5];
};
__global__ __launch_bounds__(256) void wt_all_kernel(WtJobs a) {
    int j = 0;
#pragma unroll
    for (int k = 1; k < 4; k++) if ((int)blockIdx.x >= a.start[k]) j = k;
    const int local = blockIdx.x - a.start[j];
    const int N = a.N[j], K = a.K[j];
    const int n0 = (local % a.ntx[j]) * 32, k0 = (local / a.ntx[j]) * 32;
    const float* __restrict__ src = a.src[j];
    u16* __restrict__ dst = a.dst[j];
    __shared__ float tile[32][33];
    int tx = threadIdx.x & 31, ty = threadIdx.x >> 5;  // 32 x 8
#pragma unroll
    for (int i = 0; i < 32; i += 8)
        tile[ty + i][tx] = src[(size_t)(k0 + ty + i) * N + n0 + tx];
    __syncthreads();
#pragma unroll
    for (int i = 0; i < 32; i += 8)
        dst[(size_t)(n0 + ty + i) * K + k0 + tx] = f2bf(tile[tx][ty + i]);
}

// ---------------- fused router + LN1: one pass over x ----------------
__global__ __launch_bounds__(256) void routerln_kernel(const float* __restrict__ x,
                                                       const float* __restrict__ Wr,
                                                       const float* __restrict__ gw,
                                                       const float* __restrict__ bw,
                                                       float* __restrict__ probs,
                                                       u16* __restrict__ xn) {
    int wv = threadIdx.x >> 6, lane = threadIdx.x & 63;
    size_t t = (size_t)blockIdx.x * 4 + wv;
    const float4* xr = (const float4*)(x + t * 768);
    const float4* wr4 = (const float4*)Wr;
    float4 v[3]; float s = 0, s2 = 0, a0 = 0, a1 = 0, a2 = 0, a3 = 0;
#pragma unroll
    for (int i = 0; i < 3; i++) {
        int f4 = lane + 64 * i;
        v[i] = xr[f4];
        s += v[i].x + v[i].y + v[i].z + v[i].w;
        s2 += v[i].x * v[i].x + v[i].y * v[i].y + v[i].z * v[i].z + v[i].w * v[i].w;
#pragma unroll
        for (int jj = 0; jj < 4; jj++) {
            float xv = (jj == 0) ? v[i].x : (jj == 1) ? v[i].y : (jj == 2) ? v[i].z : v[i].w;
            float4 w = wr4[f4 * 4 + jj];
            a0 = fmaf(xv, w.x, a0); a1 = fmaf(xv, w.y, a1);
            a2 = fmaf(xv, w.z, a2); a3 = fmaf(xv, w.w, a3);
        }
    }
#pragma unroll
    for (int m = 1; m < 64; m <<= 1) {
        s += __shfl_xor(s, m); s2 += __shfl_xor(s2, m);
        a0 += __shfl_xor(a0, m); a1 += __shfl_xor(a1, m);
        a2 += __shfl_xor(a2, m); a3 += __shfl_xor(a3, m);
    }
    float mx = fmaxf(fmaxf(a0, a1), fmaxf(a2, a3));
    float e0 = expf(a0 - mx), e1 = expf(a1 - mx), e2 = expf(a2 - mx), e3 = expf(a3 - mx);
    float inv = 1.f / (e0 + e1 + e2 + e3);
    if (lane < 4) {
        float pv = (lane == 0) ? e0 : (lane == 1) ? e1 : (lane == 2) ? e2 : e3;
        int b = (int)(t >> 11), n = (int)(t & 2047);
        probs[(size_t)(b * 4 + lane) * 2048 + n] = pv * inv;
    }
    float mu = s * (1.f / 768.f);
    float var = s2 * (1.f / 768.f) - mu * mu;
    float rs = rsqrtf(var + 1e-5f);
    uint2* op = (uint2*)(xn + t * 768);
#pragma unroll
    for (int i = 0; i < 3; i++) {
        int j4 = (lane + 64 * i) * 4;
        float y0 = (v[i].x - mu) * rs * gw[j4 + 0] + bw[j4 + 0];
        float y1 = (v[i].y - mu) * rs * gw[j4 + 1] + bw[j4 + 1];
        float y2 = (v[i].z - mu) * rs * gw[j4 + 2] + bw[j4 + 2];
        float y3 = (v[i].w - mu) * rs * gw[j4 + 3] + bw[j4 + 3];
        uint2 o; o.x = cvt_pk_bf16(y0, y1); o.y = cvt_pk_bf16(y2, y3);
        op[lane + 64 * i] = o;
    }
}

// ---------------- top-512 per (b,e) via in-LDS bitonic sort ----------------
__global__ __launch_bounds__(1024) void topk_kernel(const float* __restrict__ probs,
                                                    int* __restrict__ idx, float* __restrict__ gate,
                                                    int* __restrict__ rev) {
    int be = blockIdx.x; int b = be >> 2, e = be & 3;
    __shared__ u64 keys[2048];
    for (int n = threadIdx.x; n < 2048; n += 1024) {
        u32 p = __builtin_bit_cast(u32, probs[(size_t)be * 2048 + n]);
        keys[n] = ((u64)p << 32) | (u32)(2047 - n);
        rev[((size_t)b * 2048 + n) * 4 + e] = -1;
    }
    __syncthreads();
    for (int k = 2; k <= 2048; k <<= 1)
        for (int j = k >> 1; j > 0; j >>= 1) {
            for (int i = threadIdx.x; i < 2048; i += 1024) {
                int ixj = i ^ j;
                if (ixj > i) {
                    u64 a = keys[i], bb = keys[ixj];
                    bool up = ((i & k) == 0);
                    if (up ? (a < bb) : (a > bb)) { keys[i] = bb; keys[ixj] = a; }
                }
            }
            __syncthreads();
        }
    for (int c = threadIdx.x; c < 512; c += 1024) {
        u64 kk = keys[c];
        int n = 2047 - (int)(kk & 0xffffffffu);
        idx[be * 512 + c] = n;
        gate[be * 512 + c] = __builtin_bit_cast(float, (u32)(kk >> 32));
        rev[((size_t)b * 2048 + n) * 4 + e] = c;
    }
}

// ---------------- fused multi-expert bf16 GEMM ----------------
// 1D grid, bz-pinned XCD decode: bid = ((s*4 + mt) * 8) + bz.
// Swapped-operand MFMA for q/k + MODE1/2 => packed uint2 C-stores.
struct GemmJobs {
    const u16* A[4]; u16* C[4]; u16* VT[4]; const int* idx[4];
    const u16* BT; const float* bias;
    long sAb[4], sCb[4], sVb[4];
    int lda[4], ldc[4], nk[4], nmask[4], tps[4], tstart[4];
    int ldb;
};

template <int MODE>
__global__ __launch_bounds__(256) void gemm_kernel(GemmJobs a) {
    __shared__ __align__(16) char smem[2][16384];
    const int tid = threadIdx.x, wv = tid >> 6, lane = tid & 63;
    const int bid = blockIdx.x;
    const int bz = bid & 7;
    const int mt = (bid >> 3) & 3;
    const int sidx = bid >> 5;
    int e = 0;
#pragma unroll
    for (int k = 1; k < 4; k++) if (sidx >= a.tstart[k]) e = k;
    const int local = sidx - a.tstart[e];
    int seg, ntl;
    if (MODE == 0) { seg = local / a.tps[e]; ntl = local - seg * a.tps[e]; }
    else { seg = 0; ntl = local; }
    const int nbase = seg * 768 + ntl * 128;
    const int lda = a.lda[e], ldc = a.ldc[e], nk = a.nk[e], nmask = a.nmask[e];
    const u16* Ap = a.A[e] + (long)bz * a.sAb[e];
    const int* ix = a.idx[e] ? (a.idx[e] + bz * 2048) : nullptr;
    const bool swapped = (MODE != 0) || (seg < 2);

    auto stage = [&](int buf, int kt) {
        char* base = smem[buf] + ((wv >= 2) ? 8192 : 0);
        const int kb = kt * 32;
#pragma unroll
        for (int q = 0; q < 4; q++) {
            int i8 = (wv & 1) * 4 + q;
            int row = i8 * 16 + (lane >> 2);
            int clog = ((lane & 3) * 16) ^ ((row & 6) << 3);
            const u16* g;
            if (wv < 2) {
                int rs = ix ? ix[mt * 128 + row] : (mt * 128 + row);
                g = Ap + (long)rs * lda + kb;
            } else {
                g = a.BT + (long)(nbase + row) * a.ldb + kb;
            }
            GLOAD_LDS16((const char*)g + clog, base + i8 * 1024);
        }
    };

    f32x4 acc[4][4] = {};
    stage(0, 0);
    __syncthreads();
    int buf = 0;
    const int wr = wv >> 1, wc = wv & 1;
    const int l15 = lane & 15, lg = lane >> 4;
    const int cb = lg * 16;
    for (int kt = 0; kt < nk; kt++) {
        if (kt + 1 < nk) stage(buf ^ 1, kt + 1);
        const char* ab = smem[buf];
        const char* bb = smem[buf] + 8192;
        bf16x8 af[4], bfv[4];
#pragma unroll
        for (int mi = 0; mi < 4; mi++) {
            int r = wr * 64 + mi * 16 + l15;
            af[mi] = *(const bf16x8*)(ab + r * 64 + (cb ^ ((r & 6) << 3)));
        }
#pragma unroll
        for (int ni = 0; ni < 4; ni++) {
            int r = wc * 64 + ni * 16 + l15;
            bfv[ni] = *(const bf16x8*)(bb + r * 64 + (cb ^ ((r & 6) << 3)));
        }
        if (swapped) {
#pragma unroll
            for (int mi = 0; mi < 4; mi++)
#pragma unroll
                for (int ni = 0; ni < 4; ni++)
                    acc[mi][ni] = __builtin_amdgcn_mfma_f32_16x16x32_bf16(bfv[ni], af[mi], acc[mi][ni], 0, 0, 0);
        } else {
#pragma unroll
            for (int mi = 0; mi < 4; mi++)
#pragma unroll
                for (int ni = 0; ni < 4; ni++)
                    acc[mi][ni] = __builtin_amdgcn_mfma_f32_16x16x32_bf16(af[mi], bfv[ni], acc[mi][ni], 0, 0, 0);
        }
        __syncthreads();
        buf ^= 1;
    }

    u16* Cb = a.C[e] + (long)bz * a.sCb[e];
    if (MODE == 0 && seg == 2) {
        // V stored transposed [feature][token], original operand order
        u16* Vb = a.VT[e] + (long)bz * a.sVb[e];
#pragma unroll
        for (int mi = 0; mi < 4; mi++) {
            const int r0 = mt * 128 + wr * 64 + mi * 16 + (lg << 2);
#pragma unroll
            for (int ni = 0; ni < 4; ni++) {
                const int nloc = ntl * 128 + wc * 64 + ni * 16 + l15;
                const bool act = nloc < nmask;
                uint2 pv;
                if (act) { pv.x = cvt_pk_bf16(acc[mi][ni][0], acc[mi][ni][1]);
                           pv.y = cvt_pk_bf16(acc[mi][ni][2], acc[mi][ni][3]); }
                else { pv.x = 0; pv.y = 0; }
                *(uint2*)(Vb + (long)nloc * 512 + r0) = pv;
            }
        }
    } else if (MODE == 0) {
        // q,k: swapped => lane holds row = ..+l15, 4 consecutive cols
#pragma unroll
        for (int mi = 0; mi < 4; mi++) {
            const int row = mt * 128 + wr * 64 + mi * 16 + l15;
            u16* cp = Cb + (long)row * 1536 + seg * 768 + ntl * 128;
#pragma unroll
            for (int ni = 0; ni < 4; ni++) {
                const int colb = wc * 64 + ni * 16 + lg * 4;
                const bool act = (ntl * 128 + colb) < nmask;
                uint2 pv;
                if (act) { pv.x = cvt_pk_bf16(acc[mi][ni][0], acc[mi][ni][1]);
                           pv.y = cvt_pk_bf16(acc[mi][ni][2], acc[mi][ni][3]); }
                else { pv.x = 0; pv.y = 0; }
                *(uint2*)(cp + colb) = pv;
            }
        }
    } else {
#pragma unroll
        for (int mi = 0; mi < 4; mi++) {
            const int row = mt * 128 + wr * 64 + mi * 16 + l15;
#pragma unroll
            for (int ni = 0; ni < 4; ni++) {
                const int nloc = ntl * 128 + wc * 64 + ni * 16 + lg * 4;
                const float4 bv = *(const float4*)(a.bias + nloc);
                float v0 = acc[mi][ni][0] + bv.x, v1 = acc[mi][ni][1] + bv.y;
                float v2 = acc[mi][ni][2] + bv.z, v3 = acc[mi][ni][3] + bv.w;
                if (MODE == 2) { v0 = gelu_f(v0); v1 = gelu_f(v1); v2 = gelu_f(v2); v3 = gelu_f(v3); }
                uint2 pv; pv.x = cvt_pk_bf16(v0, v1); pv.y = cvt_pk_bf16(v2, v3);
                *(uint2*)(Cb + (long)row * ldc + nloc) = pv;
            }
        }
    }
}

// ---------------- flash attention, barrier-free, direct-global operands ----------------
// bid = qt*184 + job (184 % 8 == 0 -> the 4 qt siblings of a head share an XCD/L2).
// K/V per (job,head) = 128 KB, L2-resident & shared by the 4 siblings -> NO LDS
// staging, NO barriers: MFMA operands read 16B/lane straight from global (L2 hit).
// O written via per-wave-private LDS transpose -> coalesced 16B/lane stores.
__global__ __launch_bounds__(256) void attn_kernel(const u16* __restrict__ qkv,
                                                   const u16* __restrict__ vt,
                                                   u16* __restrict__ obuf) {
    const int bid = blockIdx.x;
    const int jobl = bid % 184;     // b*23 + hj
    const int qt = bid / 184;
    const int b = jobl / 23, hj = jobl % 23;
    int e, h;
    if (hj < 12) { e = 0; h = hj; }
    else if (hj < 18) { e = 1; h = hj - 12; }
    else if (hj < 21) { e = 2; h = hj - 18; }
    else { e = 3; h = hj - 21; }
    const int job = b * 4 + e;
    const u16* qkvj = qkv + (size_t)job * 512 * 1536;
    const u16* vtj = vt + (size_t)job * 768 * 512 + (size_t)h * 64 * 512;
    u16* oj = obuf + (size_t)job * 512 * 768;
    __shared__ __align__(16) char lds[16384];   // O-transpose only, wave-private 4KB
    const int tid = threadIdx.x, wv = tid >> 6;
    const int lane = tid & 63, l15 = lane & 15, lg = lane >> 4;
    const int q0 = qt * 128 + wv * 32;

    bf16x8 qf[2][2];
#pragma unroll
    for (int n2 = 0; n2 < 2; n2++)
#pragma unroll
        for (int ks = 0; ks < 2; ks++)
            qf[n2][ks] = *(const bf16x8*)(qkvj + (size_t)(q0 + n2 * 16 + l15) * 1536 + h * 64 + ks * 32 + lg * 8);

    f32x4 oacc[4][2] = {};
    float mrun[2] = {-1e30f, -1e30f}, lrun[2] = {0.f, 0.f};
    const float SA = 0.18033688011112042f;  // 0.125 * log2(e)

    for (int t = 0; t < 4; t++) {
        const int kv0 = t * 128;

        f32x4 sacc[8][2] = {};
#pragma unroll
        for (int ks = 0; ks < 2; ks++)
#pragma unroll
            for (int m8 = 0; m8 < 8; m8++) {
                bf16x8 kf = *(const bf16x8*)(qkvj + (size_t)(kv0 + m8 * 16 + l15) * 1536 + 768 + h * 64 + ks * 32 + lg * 8);
#pragma unroll
                for (int n2 = 0; n2 < 2; n2++)
                    sacc[m8][n2] = __builtin_amdgcn_mfma_f32_16x16x32_bf16(kf, qf[n2][ks], sacc[m8][n2], 0, 0, 0);
            }

        u32 pk[8][2][2];
#pragma unroll
        for (int n2 = 0; n2 < 2; n2++) {
            float pm[8];
#pragma unroll
            for (int m8 = 0; m8 < 8; m8++)
                pm[m8] = fmaxf(fmaxf(sacc[m8][n2][0], sacc[m8][n2][1]),
                               fmaxf(sacc[m8][n2][2], sacc[m8][n2][3]));
            float tm = fmaxf(fmaxf(fmaxf(pm[0], pm[1]), fmaxf(pm[2], pm[3])),
                             fmaxf(fmaxf(pm[4], pm[5]), fmaxf(pm[6], pm[7])));
            tm = fmaxf(tm, __shfl_xor(tm, 16));
            tm = fmaxf(tm, __shfl_xor(tm, 32));
            float mnew = fmaxf(mrun[n2], tm);
            float alpha = exp2f((mrun[n2] - mnew) * SA);
            float ps[8];
#pragma unroll
            for (int m8 = 0; m8 < 8; m8++) {
#pragma unroll
                for (int j = 0; j < 4; j++)
                    sacc[m8][n2][j] = exp2f((sacc[m8][n2][j] - mnew) * SA);
                ps[m8] = (sacc[m8][n2][0] + sacc[m8][n2][1]) + (sacc[m8][n2][2] + sacc[m8][n2][3]);
            }
            float tsum = ((ps[0] + ps[1]) + (ps[2] + ps[3])) + ((ps[4] + ps[5]) + (ps[6] + ps[7]));
            tsum += __shfl_xor(tsum, 16);
            tsum += __shfl_xor(tsum, 32);
            lrun[n2] = lrun[n2] * alpha + tsum;
            mrun[n2] = mnew;
#pragma unroll
            for (int mo = 0; mo < 4; mo++) oacc[mo][n2] *= alpha;
#pragma unroll
            for (int m8 = 0; m8 < 8; m8++) {
                pk[m8][n2][0] = cvt_pk_bf16(sacc[m8][n2][0], sacc[m8][n2][1]);
                pk[m8][n2][1] = cvt_pk_bf16(sacc[m8][n2][2], sacc[m8][n2][3]);
            }
        }

        const int la = ((2 * lg) & 3) * 16 + l15;
        const int lb = ((2 * lg + 1) & 3) * 16 + l15;
#pragma unroll
        for (int kb = 0; kb < 4; kb++) {
            bf16x8 pb[2];
#pragma unroll
            for (int n2 = 0; n2 < 2; n2++) {
                u32 w[4];
#pragma unroll
                for (int half = 0; half < 2; half++) {
                    int src = (half == 0) ? la : lb;
                    u32 aA = (u32)__shfl((int)pk[2 * kb + 0][n2][0], src);
                    u32 aB = (u32)__shfl((int)pk[2 * kb + 1][n2][0], src);
                    u32 bA = (u32)__shfl((int)pk[2 * kb + 0][n2][1], src);
                    u32 bB = (u32)__shfl((int)pk[2 * kb + 1][n2][1], src);
                    w[half * 2 + 0] = (lg < 2) ? aA : aB;
                    w[half * 2 + 1] = (lg < 2) ? bA : bB;
                }
                U4 uw{w[0], w[1], w[2], w[3]};
                pb[n2] = __builtin_bit_cast(bf16x8, uw);
            }
#pragma unroll
            for (int mo = 0; mo < 4; mo++) {
                bf16x8 vf = *(const bf16x8*)(vtj + (size_t)(mo * 16 + l15) * 512 + kv0 + kb * 32 + lg * 8);
#pragma unroll
                for (int n2 = 0; n2 < 2; n2++)
                    oacc[mo][n2] = __builtin_amdgcn_mfma_f32_16x16x32_bf16(vf, pb[n2], oacc[mo][n2], 0, 0, 0);
            }
        }
    }

    // ---- O epilogue: per-wave-private LDS transpose -> coalesced 16B/lane stores ----
    char* Wl = lds + wv * 4096;            // wave-private [32 c][128 B]
#pragma unroll
    for (int n2 = 0; n2 < 2; n2++) {
        float inv = 1.f / lrun[n2];
        int c = n2 * 16 + l15;
#pragma unroll
        for (int mo = 0; mo < 4; mo++) {
            int tch = mo * 2 + (lg >> 1);  // 16B slot index 0..7
            int byteoff = c * 128 + (((tch ^ (c & 7)) << 4)) + (lg & 1) * 8;
            uint2 o;
            o.x = cvt_pk_bf16(oacc[mo][n2][0] * inv, oacc[mo][n2][1] * inv);
            o.y = cvt_pk_bf16(oacc[mo][n2][2] * inv, oacc[mo][n2][3] * inv);
            *(uint2*)(Wl + byteoff) = o;
        }
    }
    asm volatile("s_waitcnt lgkmcnt(0)" ::: "memory");
    __builtin_amdgcn_sched_barrier(0);
#pragma unroll
    for (int p = 0; p < 4; p++) {
        int row = p * 8 + (lane >> 3);
        int tch = lane & 7;
        uint4 v = *(const uint4*)(Wl + row * 128 + ((tch ^ (row & 7)) << 4));
        *(uint4*)(oj + (size_t)(q0 + row) * 768 + h * 64 + tch * 8) = v;
    }
}

// ---------------- combine (+ optional fused LN) ----------------
// 4 tokens per 256-thread block (one per wave). MUST be launched <<<4096, 256>>>.
template <int DO_LN>
__global__ __launch_bounds__(256) void combineln_kernel(const float* __restrict__ basex,
                                                        float* __restrict__ outp,
                                                        const u16* __restrict__ ye,
                                                        const int* __restrict__ rev,
                                                        const float* __restrict__ gate,
                                                        const float* __restrict__ gw,
                                                        const float* __restrict__ bw,
                                                        u16* __restrict__ xn) {
    int wv = threadIdx.x >> 6, lane = threadIdx.x & 63;
    size_t t = (size_t)blockIdx.x * 4 + wv;
    const int b = (int)(t >> 11);
    const int4 rv = *(const int4*)(rev + t * 4);
    const int cs[4] = {rv.x, rv.y, rv.z, rv.w};
    float4 v[3];
#pragma unroll
    for (int i = 0; i < 3; i++) v[i] = *(const float4*)(basex + t * 768 + (lane + 64 * i) * 4);
#pragma unroll
    for (int e = 0; e < 4; e++) {
        const int c = cs[e];
        if (c >= 0) {
            const int job = b * 4 + e;
            const float g = gate[job * 512 + c];
            const u16* yr = ye + ((size_t)job * 512 + c) * 768;
#pragma unroll
            for (int i = 0; i < 3; i++) {
                int f4 = lane + 64 * i;
                if (f4 < (192 >> e)) {
                    uint2 raw = *(const uint2*)(yr + f4 * 4);
                    v[i].x += g * bf2f(raw.x & 0xffffu);
                    v[i].y += g * bf2f(raw.x >> 16);
                    v[i].z += g * bf2f(raw.y & 0xffffu);
                    v[i].w += g * bf2f(raw.y >> 16);
                }
            }
        }
    }
#pragma unroll
    for (int i = 0; i < 3; i++) *(float4*)(outp + t * 768 + (lane + 64 * i) * 4) = v[i];
    if (DO_LN) {
        float s = 0, s2 = 0;
#pragma unroll
        for (int i = 0; i < 3; i++) {
            s += v[i].x + v[i].y + v[i].z + v[i].w;
            s2 += v[i].x * v[i].x + v[i].y * v[i].y + v[i].z * v[i].z + v[i].w * v[i].w;
        }
#pragma unroll
        for (int m = 1; m < 64; m <<= 1) { s += __shfl_xor(s, m); s2 += __shfl_xor(s2, m); }
        float mu = s * (1.f / 768.f);
        float var = s2 * (1.f / 768.f) - mu * mu;
        float rs = rsqrtf(var + 1e-5f);
        uint2* op = (uint2*)(xn + t * 768);
#pragma unroll
        for (int i = 0; i < 3; i++) {
            int j4 = (lane + 64 * i) * 4;
            float y0 = (v[i].x - mu) * rs * gw[j4 + 0] + bw[j4 + 0];
            float y1 = (v[i].y - mu) * rs * gw[j4 + 1] + bw[j4 + 1];
            float y2 = (v[i].z - mu) * rs * gw[j4 + 2] + bw[j4 + 2];
            float y3 = (v[i].w - mu) * rs * gw[j4 + 3] + bw[j4 + 3];
            uint2 o; o.x = cvt_pk_bf16(y0, y1); o.y = cvt_pk_bf16(y2, y3);
            op[lane + 64 * i] = o;
        }
    }
}

// ============================================================================
extern "C" void kernel_launch(void* const* d_in, const int* in_sizes, int n_in,
                              void* d_out, int out_size, void* d_ws, size_t ws_size,
                              hipStream_t stream) {
    (void)in_sizes; (void)n_in; (void)out_size; (void)ws_size;
    const float* x     = (const float*)d_in[0];
    const float* Wr    = (const float*)d_in[1];
    const float* ln1g  = (const float*)d_in[2];
    const float* ln1b  = (const float*)d_in[3];
    const float* ln2g  = (const float*)d_in[4];
    const float* ln2b  = (const float*)d_in[5];
    const float* Wqkv  = (const float*)d_in[6];
    const float* Wproj = (const float*)d_in[7];
    const float* bproj = (const float*)d_in[8];
    const float* W1    = (const float*)d_in[9];
    const float* b1    = (const float*)d_in[10];
    const float* W2    = (const float*)d_in[11];
    const float* b2    = (const float*)d_in[12];
    float* outp = (float*)d_out;

    char* ws = (char*)d_ws;
    size_t off = 0;
    auto take = [&](size_t bytes) -> void* {
        void* p = ws + off;
        off += (bytes + 255) & ~(size_t)255;
        return p;
    };
    u16*   WqkvT  = (u16*)take((size_t)2304 * 768 * 2);
    u16*   WprojT = (u16*)take((size_t)768 * 768 * 2);
    u16*   W1T    = (u16*)take((size_t)3072 * 768 * 2);
    u16*   W2T    = (u16*)take((size_t)768 * 3072 * 2);
    float* probs  = (float*)take((size_t)32 * 2048 * 4);
    int*   idxb   = (int*)take((size_t)32 * 512 * 4);
    float* gateb  = (float*)take((size_t)32 * 512 * 4);
    int*   revb   = (int*)take((size_t)8 * 2048 * 4 * 4);
    u16*   xn     = (u16*)take((size_t)8 * 2048 * 768 * 2);
    u16*   qkvb   = (u16*)take((size_t)32 * 512 * 1536 * 2);  // aliased as h-pool in MLP phase
    u16*   vtb    = (u16*)take((size_t)32 * 768 * 512 * 2);
    u16*   ob     = (u16*)take((size_t)32 * 512 * 768 * 2);
    u16*   yeb    = (u16*)take((size_t)32 * 512 * 768 * 2);
    u16*   hb     = qkvb;

    const int Dk_[4] = {768, 384, 192, 96};
    const int He_[4] = {3072, 1536, 768, 384};
    size_t eoffH[4];
    { size_t s = 0; for (int e = 0; e < 4; e++) { eoffH[e] = s; s += (size_t)8 * 512 * He_[e]; } }

    // --- weight transposes (one launch) ---
    WtJobs wj{};
    wj.src[0] = Wqkv;  wj.dst[0] = WqkvT;  wj.K[0] = 768;  wj.N[0] = 2304;
    wj.src[1] = Wproj; wj.dst[1] = WprojT; wj.K[1] = 768;  wj.N[1] = 768;
    wj.src[2] = W1;    wj.dst[2] = W1T;    wj.K[2] = 768;  wj.N[2] = 3072;
    wj.src[3] = W2;    wj.dst[3] = W2T;    wj.K[3] = 3072; wj.N[3] = 768;
    { int s = 0; for (int j = 0; j < 4; j++) { wj.ntx[j] = wj.N[j] / 32; wj.start[j] = s; s += (wj.N[j] / 32) * (wj.K[j] / 32); } wj.start[4] = s;
      wt_all_kernel<<<s, 256, 0, stream>>>(wj); }

    routerln_kernel<<<4096, 256, 0, stream>>>(x, Wr, ln1g, ln1b, probs, xn);
    topk_kernel<<<32, 1024, 0, stream>>>(probs, idxb, gateb, revb);

    // --- qkv (fused experts) ---
    {
        GemmJobs ga{};
        ga.BT = WqkvT; ga.bias = nullptr; ga.ldb = 768;
        int s = 0;
        for (int e = 0; e < 4; e++) {
            int tps = (Dk_[e] + 127) / 128;
            ga.A[e] = xn; ga.C[e] = qkvb + (size_t)e * 512 * 1536; ga.VT[e] = vtb + (size_t)e * 768 * 512;
            ga.idx[e] = idxb + e * 512;
            ga.sAb[e] = (long)2048 * 768; ga.sCb[e] = (long)4 * 512 * 1536; ga.sVb[e] = (long)4 * 768 * 512;
            ga.lda[e] = 768; ga.ldc[e] = 1536; ga.nk[e] = Dk_[e] / 32; ga.nmask[e] = Dk_[e];
            ga.tps[e] = tps; ga.tstart[e] = s; s += 3 * tps;
        }
        gemm_kernel<0><<<s * 32, 256, 0, stream>>>(ga);
    }

    attn_kernel<<<736, 256, 0, stream>>>(qkvb, vtb, ob);

    // --- proj (fused experts) ---
    {
        GemmJobs ga{};
        ga.BT = WprojT; ga.bias = bproj; ga.ldb = 768;
        int s = 0;
        for (int e = 0; e < 4; e++) {
            int tps = (Dk_[e] + 127) / 128;
            ga.A[e] = ob + (size_t)e * 512 * 768; ga.C[e] = yeb + (size_t)e * 512 * 768;
            ga.VT[e] = nullptr; ga.idx[e] = nullptr;
            ga.sAb[e] = (long)4 * 512 * 768; ga.sCb[e] = (long)4 * 512 * 768; ga.sVb[e] = 0;
            ga.lda[e] = 768; ga.ldc[e] = 768; ga.nk[e] = Dk_[e] / 32; ga.nmask[e] = 768;
            ga.tps[e] = tps; ga.tstart[e] = s; s += tps;
        }
        gemm_kernel<1><<<s * 32, 256, 0, stream>>>(ga);
    }

    combineln_kernel<1><<<4096, 256, 0, stream>>>(x, outp, yeb, revb, gateb, ln2g, ln2b, xn);

    // --- mlp1 (fused experts) ---
    {
        GemmJobs ga{};
        ga.BT = W1T; ga.bias = b1; ga.ldb = 768;
        int s = 0;
        for (int e = 0; e < 4; e++) {
            ga.A[e] = xn; ga.C[e] = hb + eoffH[e]; ga.VT[e] = nullptr; ga.idx[e] = idxb + e * 512;
            ga.sAb[e] = (long)2048 * 768; ga.sCb[e] = (long)512 * He_[e]; ga.sVb[e] = 0;
            ga.lda[e] = 768; ga.ldc[e] = He_[e]; ga.nk[e] = Dk_[e] / 32; ga.nmask[e] = He_[e];
            ga.tps[e] = He_[e] / 128; ga.tstart[e] = s; s += He_[e] / 128;
        }
        gemm_kernel<2><<<s * 32, 256, 0, stream>>>(ga);
    }
    // --- mlp2 (fused experts) ---
    {
        GemmJobs ga{};
        ga.BT = W2T; ga.bias = b2; ga.ldb = 3072;
        int s = 0;
        for (int e = 0; e < 4; e++) {
            int tps = (Dk_[e] + 127) / 128;
            ga.A[e] = hb + eoffH[e]; ga.C[e] = yeb + (size_t)e * 512 * 768;
            ga.VT[e] = nullptr; ga.idx[e] = nullptr;
            ga.sAb[e] = (long)512 * He_[e]; ga.sCb[e] = (long)4 * 512 * 768; ga.sVb[e] = 0;
            ga.lda[e] = He_[e]; ga.ldc[e] = 768; ga.nk[e] = He_[e] / 32; ga.nmask[e] = 768;
            ga.tps[e] = tps; ga.tstart[e] = s; s += tps;
        }
        gemm_kernel<1><<<s * 32, 256, 0, stream>>>(ga);
    }

    combineln_kernel<0><<<4096, 256, 0, stream>>>(outp, outp, yeb, revb, gateb, nullptr, nullptr, nullptr);
}

// Round 7
// 449.965 us; speedup vs baseline: 1.1327x; 1.1327x over previous
//
#include <hip/hip_runtime.h>
#include <stdint.h>

typedef uint16_t u16;
typedef uint32_t u32;
typedef uint64_t u64;
typedef float f32x4 __attribute__((ext_vector_type(4)));
typedef __bf16 bf16x8 __attribute__((ext_vector_type(8)));

#define DEVI __device__ __forceinline__

struct U4 { u32 a, b, c, d; };

DEVI u16 f2bf(float f) {
    u32 u = __builtin_bit_cast(u32, f);
    return (u16)((u + 0x7FFFu + ((u >> 16) & 1u)) >> 16);
}
DEVI float bf2f(u32 h) { return __builtin_bit_cast(float, h << 16); }
DEVI u32 cvt_pk_bf16(float lo, float hi) {
    u32 r;
    asm("v_cvt_pk_bf16_f32 %0, %1, %2" : "=v"(r) : "v"(lo), "v"(hi));
    return r;
}

DEVI float gelu_f(float x) {
    float u = 0.7978845608028654f * (x + 0.044715f * x * x * x);
    float t = exp2f(u * 2.885390081777927f);
    return x * (1.f - 1.f / (t + 1.f));
}

#define GLOAD_LDS16(gp, lp) \
    __builtin_amdgcn_global_load_lds((const __attribute__((address_space(1))) void*)(gp), \
                                     (__attribute__((address_space(3))) void*)(lp), 16, 0, 0)

// ---------------- fused weight transposes fp32[K][N] -> bf16[N][K] ----------------
struct WtJobs {
    const float* src[4]; u16* dst[4];
    int K[4], N[4], ntx[4], start[5];
};
__global__ __launch_bounds__(256) void wt_all_kernel(WtJobs a) {
    int j = 0;
#pragma unroll
    for (int k = 1; k < 4; k++) if ((int)blockIdx.x >= a.start[k]) j = k;
    const int local = blockIdx.x - a.start[j];
    const int N = a.N[j], K = a.K[j];
    const int n0 = (local % a.ntx[j]) * 32, k0 = (local / a.ntx[j]) * 32;
    const float* __restrict__ src = a.src[j];
    u16* __restrict__ dst = a.dst[j];
    __shared__ float tile[32][33];
    int tx = threadIdx.x & 31, ty = threadIdx.x >> 5;  // 32 x 8
#pragma unroll
    for (int i = 0; i < 32; i += 8)
        tile[ty + i][tx] = src[(size_t)(k0 + ty + i) * N + n0 + tx];
    __syncthreads();
#pragma unroll
    for (int i = 0; i < 32; i += 8)
        dst[(size_t)(n0 + ty + i) * K + k0 + tx] = f2bf(tile[tx][ty + i]);
}

// ---------------- fused router + LN1: one pass over x ----------------
__global__ __launch_bounds__(256) void routerln_kernel(const float* __restrict__ x,
                                                       const float* __restrict__ Wr,
                                                       const float* __restrict__ gw,
                                                       const float* __restrict__ bw,
                                                       float* __restrict__ probs,
                                                       u16* __restrict__ xn) {
    int wv = threadIdx.x >> 6, lane = threadIdx.x & 63;
    size_t t = (size_t)blockIdx.x * 4 + wv;
    const float4* xr = (const float4*)(x + t * 768);
    const float4* wr4 = (const float4*)Wr;
    float4 v[3]; float s = 0, s2 = 0, a0 = 0, a1 = 0, a2 = 0, a3 = 0;
#pragma unroll
    for (int i = 0; i < 3; i++) {
        int f4 = lane + 64 * i;
        v[i] = xr[f4];
        s += v[i].x + v[i].y + v[i].z + v[i].w;
        s2 += v[i].x * v[i].x + v[i].y * v[i].y + v[i].z * v[i].z + v[i].w * v[i].w;
#pragma unroll
        for (int jj = 0; jj < 4; jj++) {
            float xv = (jj == 0) ? v[i].x : (jj == 1) ? v[i].y : (jj == 2) ? v[i].z : v[i].w;
            float4 w = wr4[f4 * 4 + jj];
            a0 = fmaf(xv, w.x, a0); a1 = fmaf(xv, w.y, a1);
            a2 = fmaf(xv, w.z, a2); a3 = fmaf(xv, w.w, a3);
        }
    }
#pragma unroll
    for (int m = 1; m < 64; m <<= 1) {
        s += __shfl_xor(s, m); s2 += __shfl_xor(s2, m);
        a0 += __shfl_xor(a0, m); a1 += __shfl_xor(a1, m);
        a2 += __shfl_xor(a2, m); a3 += __shfl_xor(a3, m);
    }
    float mx = fmaxf(fmaxf(a0, a1), fmaxf(a2, a3));
    float e0 = expf(a0 - mx), e1 = expf(a1 - mx), e2 = expf(a2 - mx), e3 = expf(a3 - mx);
    float inv = 1.f / (e0 + e1 + e2 + e3);
    if (lane < 4) {
        float pv = (lane == 0) ? e0 : (lane == 1) ? e1 : (lane == 2) ? e2 : e3;
        int b = (int)(t >> 11), n = (int)(t & 2047);
        probs[(size_t)(b * 4 + lane) * 2048 + n] = pv * inv;
    }
    float mu = s * (1.f / 768.f);
    float var = s2 * (1.f / 768.f) - mu * mu;
    float rs = rsqrtf(var + 1e-5f);
    uint2* op = (uint2*)(xn + t * 768);
#pragma unroll
    for (int i = 0; i < 3; i++) {
        int j4 = (lane + 64 * i) * 4;
        float y0 = (v[i].x - mu) * rs * gw[j4 + 0] + bw[j4 + 0];
        float y1 = (v[i].y - mu) * rs * gw[j4 + 1] + bw[j4 + 1];
        float y2 = (v[i].z - mu) * rs * gw[j4 + 2] + bw[j4 + 2];
        float y3 = (v[i].w - mu) * rs * gw[j4 + 3] + bw[j4 + 3];
        uint2 o; o.x = cvt_pk_bf16(y0, y1); o.y = cvt_pk_bf16(y2, y3);
        op[lane + 64 * i] = o;
    }
}

// ---------------- top-512 per (b,e) via in-LDS bitonic sort ----------------
__global__ __launch_bounds__(1024) void topk_kernel(const float* __restrict__ probs,
                                                    int* __restrict__ idx, float* __restrict__ gate,
                                                    int* __restrict__ rev) {
    int be = blockIdx.x; int b = be >> 2, e = be & 3;
    __shared__ u64 keys[2048];
    for (int n = threadIdx.x; n < 2048; n += 1024) {
        u32 p = __builtin_bit_cast(u32, probs[(size_t)be * 2048 + n]);
        keys[n] = ((u64)p << 32) | (u32)(2047 - n);
        rev[((size_t)b * 2048 + n) * 4 + e] = -1;
    }
    __syncthreads();
    for (int k = 2; k <= 2048; k <<= 1)
        for (int j = k >> 1; j > 0; j >>= 1) {
            for (int i = threadIdx.x; i < 2048; i += 1024) {
                int ixj = i ^ j;
                if (ixj > i) {
                    u64 a = keys[i], bb = keys[ixj];
                    bool up = ((i & k) == 0);
                    if (up ? (a < bb) : (a > bb)) { keys[i] = bb; keys[ixj] = a; }
                }
            }
            __syncthreads();
        }
    for (int c = threadIdx.x; c < 512; c += 1024) {
        u64 kk = keys[c];
        int n = 2047 - (int)(kk & 0xffffffffu);
        idx[be * 512 + c] = n;
        gate[be * 512 + c] = __builtin_bit_cast(float, (u32)(kk >> 32));
        rev[((size_t)b * 2048 + n) * 4 + e] = c;
    }
}

// ---------------- fused multi-expert bf16 GEMM ----------------
// 1D grid, bz-pinned XCD decode: bid = ((s*4 + mt) * 8) + bz.
// Swapped-operand MFMA for q/k + MODE1/2 => packed uint2 C-stores.
struct GemmJobs {
    const u16* A[4]; u16* C[4]; u16* VT[4]; const int* idx[4];
    const u16* BT; const float* bias;
    long sAb[4], sCb[4], sVb[4];
    int lda[4], ldc[4], nk[4], nmask[4], tps[4], tstart[4];
    int ldb;
};

template <int MODE>
__global__ __launch_bounds__(256) void gemm_kernel(GemmJobs a) {
    __shared__ __align__(16) char smem[2][16384];
    const int tid = threadIdx.x, wv = tid >> 6, lane = tid & 63;
    const int bid = blockIdx.x;
    const int bz = bid & 7;
    const int mt = (bid >> 3) & 3;
    const int sidx = bid >> 5;
    int e = 0;
#pragma unroll
    for (int k = 1; k < 4; k++) if (sidx >= a.tstart[k]) e = k;
    const int local = sidx - a.tstart[e];
    int seg, ntl;
    if (MODE == 0) { seg = local / a.tps[e]; ntl = local - seg * a.tps[e]; }
    else { seg = 0; ntl = local; }
    const int nbase = seg * 768 + ntl * 128;
    const int lda = a.lda[e], ldc = a.ldc[e], nk = a.nk[e], nmask = a.nmask[e];
    const u16* Ap = a.A[e] + (long)bz * a.sAb[e];
    const int* ix = a.idx[e] ? (a.idx[e] + bz * 2048) : nullptr;
    const bool swapped = (MODE != 0) || (seg < 2);

    auto stage = [&](int buf, int kt) {
        char* base = smem[buf] + ((wv >= 2) ? 8192 : 0);
        const int kb = kt * 32;
#pragma unroll
        for (int q = 0; q < 4; q++) {
            int i8 = (wv & 1) * 4 + q;
            int row = i8 * 16 + (lane >> 2);
            int clog = ((lane & 3) * 16) ^ ((row & 6) << 3);
            const u16* g;
            if (wv < 2) {
                int rs = ix ? ix[mt * 128 + row] : (mt * 128 + row);
                g = Ap + (long)rs * lda + kb;
            } else {
                g = a.BT + (long)(nbase + row) * a.ldb + kb;
            }
            GLOAD_LDS16((const char*)g + clog, base + i8 * 1024);
        }
    };

    f32x4 acc[4][4] = {};
    stage(0, 0);
    __syncthreads();
    int buf = 0;
    const int wr = wv >> 1, wc = wv & 1;
    const int l15 = lane & 15, lg = lane >> 4;
    const int cb = lg * 16;
    for (int kt = 0; kt < nk; kt++) {
        if (kt + 1 < nk) stage(buf ^ 1, kt + 1);
        const char* ab = smem[buf];
        const char* bb = smem[buf] + 8192;
        bf16x8 af[4], bfv[4];
#pragma unroll
        for (int mi = 0; mi < 4; mi++) {
            int r = wr * 64 + mi * 16 + l15;
            af[mi] = *(const bf16x8*)(ab + r * 64 + (cb ^ ((r & 6) << 3)));
        }
#pragma unroll
        for (int ni = 0; ni < 4; ni++) {
            int r = wc * 64 + ni * 16 + l15;
            bfv[ni] = *(const bf16x8*)(bb + r * 64 + (cb ^ ((r & 6) << 3)));
        }
        if (swapped) {
#pragma unroll
            for (int mi = 0; mi < 4; mi++)
#pragma unroll
                for (int ni = 0; ni < 4; ni++)
                    acc[mi][ni] = __builtin_amdgcn_mfma_f32_16x16x32_bf16(bfv[ni], af[mi], acc[mi][ni], 0, 0, 0);
        } else {
#pragma unroll
            for (int mi = 0; mi < 4; mi++)
#pragma unroll
                for (int ni = 0; ni < 4; ni++)
                    acc[mi][ni] = __builtin_amdgcn_mfma_f32_16x16x32_bf16(af[mi], bfv[ni], acc[mi][ni], 0, 0, 0);
        }
        __syncthreads();
        buf ^= 1;
    }

    u16* Cb = a.C[e] + (long)bz * a.sCb[e];
    if (MODE == 0 && seg == 2) {
        // V stored transposed [feature][token], original operand order
        u16* Vb = a.VT[e] + (long)bz * a.sVb[e];
#pragma unroll
        for (int mi = 0; mi < 4; mi++) {
            const int r0 = mt * 128 + wr * 64 + mi * 16 + (lg << 2);
#pragma unroll
            for (int ni = 0; ni < 4; ni++) {
                const int nloc = ntl * 128 + wc * 64 + ni * 16 + l15;
                const bool act = nloc < nmask;
                uint2 pv;
                if (act) { pv.x = cvt_pk_bf16(acc[mi][ni][0], acc[mi][ni][1]);
                           pv.y = cvt_pk_bf16(acc[mi][ni][2], acc[mi][ni][3]); }
                else { pv.x = 0; pv.y = 0; }
                *(uint2*)(Vb + (long)nloc * 512 + r0) = pv;
            }
        }
    } else if (MODE == 0) {
        // q,k: swapped => lane holds row = ..+l15, 4 consecutive cols
#pragma unroll
        for (int mi = 0; mi < 4; mi++) {
            const int row = mt * 128 + wr * 64 + mi * 16 + l15;
            u16* cp = Cb + (long)row * 1536 + seg * 768 + ntl * 128;
#pragma unroll
            for (int ni = 0; ni < 4; ni++) {
                const int colb = wc * 64 + ni * 16 + lg * 4;
                const bool act = (ntl * 128 + colb) < nmask;
                uint2 pv;
                if (act) { pv.x = cvt_pk_bf16(acc[mi][ni][0], acc[mi][ni][1]);
                           pv.y = cvt_pk_bf16(acc[mi][ni][2], acc[mi][ni][3]); }
                else { pv.x = 0; pv.y = 0; }
                *(uint2*)(cp + colb) = pv;
            }
        }
    } else {
#pragma unroll
        for (int mi = 0; mi < 4; mi++) {
            const int row = mt * 128 + wr * 64 + mi * 16 + l15;
#pragma unroll
            for (int ni = 0; ni < 4; ni++) {
                const int nloc = ntl * 128 + wc * 64 + ni * 16 + lg * 4;
                const float4 bv = *(const float4*)(a.bias + nloc);
                float v0 = acc[mi][ni][0] + bv.x, v1 = acc[mi][ni][1] + bv.y;
                float v2 = acc[mi][ni][2] + bv.z, v3 = acc[mi][ni][3] + bv.w;
                if (MODE == 2) { v0 = gelu_f(v0); v1 = gelu_f(v1); v2 = gelu_f(v2); v3 = gelu_f(v3); }
                uint2 pv; pv.x = cvt_pk_bf16(v0, v1); pv.y = cvt_pk_bf16(v2, v3);
                *(uint2*)(Cb + (long)row * ldc + nloc) = pv;
            }
        }
    }
}

// ---------------- flash attention: 8 waves x 16 q-rows, LDS-staged K/V ----------------
// bid = qt*184 + job (184 % 8 == 0 -> the qt siblings of a head share an XCD/L2).
// 512 threads; per tile: stage K[128][128B]+V^T[64][256B] (XOR-swizzled), 2 barriers.
// 16 q-rows/wave halves VGPR & per-wave serial chains, doubles wave count (5888).
// O written via per-wave-private LDS transpose -> coalesced 16B/lane stores.
__global__ __launch_bounds__(512) void attn_kernel(const u16* __restrict__ qkv,
                                                   const u16* __restrict__ vt,
                                                   u16* __restrict__ obuf) {
    const int bid = blockIdx.x;
    const int jobl = bid % 184;     // b*23 + hj
    const int qt = bid / 184;
    const int b = jobl / 23, hj = jobl % 23;
    int e, h;
    if (hj < 12) { e = 0; h = hj; }
    else if (hj < 18) { e = 1; h = hj - 12; }
    else if (hj < 21) { e = 2; h = hj - 18; }
    else { e = 3; h = hj - 21; }
    const int job = b * 4 + e;
    const u16* qkvj = qkv + (size_t)job * 512 * 1536;
    const u16* vtj = vt + (size_t)job * 768 * 512 + (size_t)h * 64 * 512;
    u16* oj = obuf + (size_t)job * 512 * 768;
    __shared__ __align__(16) char lds[32768];
    char* Klds = lds;            // [128 kv][128 B], chunk c -> slot c ^ (row&7)
    char* Vlds = lds + 16384;    // [64 dh][256 B], chunk c -> slot c ^ (row&7) (low 8)
    const int tid = threadIdx.x, wv = tid >> 6;   // 8 waves
    const int lane = tid & 63, l15 = lane & 15, lg = lane >> 4;
    const int q0 = qt * 128 + wv * 16;            // 16 q-rows per wave

    bf16x8 qf[2];
#pragma unroll
    for (int ks = 0; ks < 2; ks++)
        qf[ks] = *(const bf16x8*)(qkvj + (size_t)(q0 + l15) * 1536 + h * 64 + ks * 32 + lg * 8);

    f32x4 oacc[4] = {};
    float mrun = -1e30f, lrun = 0.f;
    const float SA = 0.18033688011112042f;  // 0.125 * log2(e)
    const int la = ((2 * lg) & 3) * 16 + l15;
    const int lb = ((2 * lg + 1) & 3) * 16 + l15;

    for (int t = 0; t < 4; t++) {
        const int kv0 = t * 128;
        __syncthreads();
        // stage: 512 threads x (2 K-chunks + 2 V-chunks) of 16B
#pragma unroll
        for (int ii = 0; ii < 2; ii++) {
            int kslot = tid + 512 * ii;
            int kr = kslot >> 3, kc = kslot & 7;
            *(uint4*)(Klds + kr * 128 + ((kc ^ (kr & 7)) << 4)) =
                *(const uint4*)(qkvj + (size_t)(kv0 + kr) * 1536 + 768 + h * 64 + kc * 8);
            int vr = kslot >> 4, vc = kslot & 15;
            *(uint4*)(Vlds + vr * 256 + ((vc ^ (vr & 7)) << 4)) =
                *(const uint4*)(vtj + (size_t)vr * 512 + kv0 + vc * 8);
        }
        __syncthreads();

        f32x4 sacc[8] = {};
#pragma unroll
        for (int ks = 0; ks < 2; ks++)
#pragma unroll
            for (int m8 = 0; m8 < 8; m8++) {
                int r = m8 * 16 + l15;
                bf16x8 kf = *(const bf16x8*)(Klds + r * 128 + ((ks * 64 + lg * 16) ^ ((r & 7) << 4)));
                sacc[m8] = __builtin_amdgcn_mfma_f32_16x16x32_bf16(kf, qf[ks], sacc[m8], 0, 0, 0);
            }

        // online softmax: lane owns q = l15, 32 P values (m8 x 4)
        float pm[8];
#pragma unroll
        for (int m8 = 0; m8 < 8; m8++)
            pm[m8] = fmaxf(fmaxf(sacc[m8][0], sacc[m8][1]), fmaxf(sacc[m8][2], sacc[m8][3]));
        float tm = fmaxf(fmaxf(fmaxf(pm[0], pm[1]), fmaxf(pm[2], pm[3])),
                         fmaxf(fmaxf(pm[4], pm[5]), fmaxf(pm[6], pm[7])));
        tm = fmaxf(tm, __shfl_xor(tm, 16));
        tm = fmaxf(tm, __shfl_xor(tm, 32));
        float mnew = fmaxf(mrun, tm);
        float alpha = exp2f((mrun - mnew) * SA);
        float ps[8];
        u32 pk[8][2];
#pragma unroll
        for (int m8 = 0; m8 < 8; m8++) {
#pragma unroll
            for (int j = 0; j < 4; j++)
                sacc[m8][j] = exp2f((sacc[m8][j] - mnew) * SA);
            ps[m8] = (sacc[m8][0] + sacc[m8][1]) + (sacc[m8][2] + sacc[m8][3]);
            pk[m8][0] = cvt_pk_bf16(sacc[m8][0], sacc[m8][1]);
            pk[m8][1] = cvt_pk_bf16(sacc[m8][2], sacc[m8][3]);
        }
        float tsum = ((ps[0] + ps[1]) + (ps[2] + ps[3])) + ((ps[4] + ps[5]) + (ps[6] + ps[7]));
        tsum += __shfl_xor(tsum, 16);
        tsum += __shfl_xor(tsum, 32);
        lrun = lrun * alpha + tsum;
        mrun = mnew;
#pragma unroll
        for (int mo = 0; mo < 4; mo++) oacc[mo] *= alpha;

#pragma unroll
        for (int kb = 0; kb < 4; kb++) {
            u32 w[4];
#pragma unroll
            for (int half = 0; half < 2; half++) {
                int src = (half == 0) ? la : lb;
                u32 aA = (u32)__shfl((int)pk[2 * kb + 0][0], src);
                u32 aB = (u32)__shfl((int)pk[2 * kb + 1][0], src);
                u32 bA = (u32)__shfl((int)pk[2 * kb + 0][1], src);
                u32 bB = (u32)__shfl((int)pk[2 * kb + 1][1], src);
                w[half * 2 + 0] = (lg < 2) ? aA : aB;
                w[half * 2 + 1] = (lg < 2) ? bA : bB;
            }
            U4 uw{w[0], w[1], w[2], w[3]};
            bf16x8 pb = __builtin_bit_cast(bf16x8, uw);
#pragma unroll
            for (int mo = 0; mo < 4; mo++) {
                int r = mo * 16 + l15;
                bf16x8 vf = *(const bf16x8*)(Vlds + r * 256 + ((kb * 64 + lg * 16) ^ ((r & 7) << 4)));
                oacc[mo] = __builtin_amdgcn_mfma_f32_16x16x32_bf16(vf, pb, oacc[mo], 0, 0, 0);
            }
        }
    }

    // ---- O epilogue: per-wave-private LDS transpose -> coalesced 16B/lane stores ----
    __syncthreads();                       // all waves done with K/V LDS
    char* Wl = lds + wv * 2048;            // wave-private [16 c][128 B]
    {
        float inv = 1.f / lrun;
        int c = l15;
#pragma unroll
        for (int mo = 0; mo < 4; mo++) {
            int tch = mo * 2 + (lg >> 1);  // 16B slot index 0..7
            int byteoff = c * 128 + (((tch ^ (c & 7)) << 4)) + (lg & 1) * 8;
            uint2 o;
            o.x = cvt_pk_bf16(oacc[mo][0] * inv, oacc[mo][1] * inv);
            o.y = cvt_pk_bf16(oacc[mo][2] * inv, oacc[mo][3] * inv);
            *(uint2*)(Wl + byteoff) = o;
        }
    }
    asm volatile("s_waitcnt lgkmcnt(0)" ::: "memory");
    __builtin_amdgcn_sched_barrier(0);
#pragma unroll
    for (int p = 0; p < 2; p++) {
        int row = p * 8 + (lane >> 3);
        int tch = lane & 7;
        uint4 v = *(const uint4*)(Wl + row * 128 + ((tch ^ (row & 7)) << 4));
        *(uint4*)(oj + (size_t)(q0 + row) * 768 + h * 64 + tch * 8) = v;
    }
}

// ---------------- combine (+ optional fused LN) ----------------
// 4 tokens per 256-thread block (one per wave). MUST be launched <<<4096, 256>>>.
template <int DO_LN>
__global__ __launch_bounds__(256) void combineln_kernel(const float* __restrict__ basex,
                                                        float* __restrict__ outp,
                                                        const u16* __restrict__ ye,
                                                        const int* __restrict__ rev,
                                                        const float* __restrict__ gate,
                                                        const float* __restrict__ gw,
                                                        const float* __restrict__ bw,
                                                        u16* __restrict__ xn) {
    int wv = threadIdx.x >> 6, lane = threadIdx.x & 63;
    size_t t = (size_t)blockIdx.x * 4 + wv;
    const int b = (int)(t >> 11);
    const int4 rv = *(const int4*)(rev + t * 4);
    const int cs[4] = {rv.x, rv.y, rv.z, rv.w};
    float4 v[3];
#pragma unroll
    for (int i = 0; i < 3; i++) v[i] = *(const float4*)(basex + t * 768 + (lane + 64 * i) * 4);
#pragma unroll
    for (int e = 0; e < 4; e++) {
        const int c = cs[e];
        if (c >= 0) {
            const int job = b * 4 + e;
            const float g = gate[job * 512 + c];
            const u16* yr = ye + ((size_t)job * 512 + c) * 768;
#pragma unroll
            for (int i = 0; i < 3; i++) {
                int f4 = lane + 64 * i;
                if (f4 < (192 >> e)) {
                    uint2 raw = *(const uint2*)(yr + f4 * 4);
                    v[i].x += g * bf2f(raw.x & 0xffffu);
                    v[i].y += g * bf2f(raw.x >> 16);
                    v[i].z += g * bf2f(raw.y & 0xffffu);
                    v[i].w += g * bf2f(raw.y >> 16);
                }
            }
        }
    }
#pragma unroll
    for (int i = 0; i < 3; i++) *(float4*)(outp + t * 768 + (lane + 64 * i) * 4) = v[i];
    if (DO_LN) {
        float s = 0, s2 = 0;
#pragma unroll
        for (int i = 0; i < 3; i++) {
            s += v[i].x + v[i].y + v[i].z + v[i].w;
            s2 += v[i].x * v[i].x + v[i].y * v[i].y + v[i].z * v[i].z + v[i].w * v[i].w;
        }
#pragma unroll
        for (int m = 1; m < 64; m <<= 1) { s += __shfl_xor(s, m); s2 += __shfl_xor(s2, m); }
        float mu = s * (1.f / 768.f);
        float var = s2 * (1.f / 768.f) - mu * mu;
        float rs = rsqrtf(var + 1e-5f);
        uint2* op = (uint2*)(xn + t * 768);
#pragma unroll
        for (int i = 0; i < 3; i++) {
            int j4 = (lane + 64 * i) * 4;
            float y0 = (v[i].x - mu) * rs * gw[j4 + 0] + bw[j4 + 0];
            float y1 = (v[i].y - mu) * rs * gw[j4 + 1] + bw[j4 + 1];
            float y2 = (v[i].z - mu) * rs * gw[j4 + 2] + bw[j4 + 2];
            float y3 = (v[i].w - mu) * rs * gw[j4 + 3] + bw[j4 + 3];
            uint2 o; o.x = cvt_pk_bf16(y0, y1); o.y = cvt_pk_bf16(y2, y3);
            op[lane + 64 * i] = o;
        }
    }
}

// ============================================================================
extern "C" void kernel_launch(void* const* d_in, const int* in_sizes, int n_in,
                              void* d_out, int out_size, void* d_ws, size_t ws_size,
                              hipStream_t stream) {
    (void)in_sizes; (void)n_in; (void)out_size; (void)ws_size;
    const float* x     = (const float*)d_in[0];
    const float* Wr    = (const float*)d_in[1];
    const float* ln1g  = (const float*)d_in[2];
    const float* ln1b  = (const float*)d_in[3];
    const float* ln2g  = (const float*)d_in[4];
    const float* ln2b  = (const float*)d_in[5];
    const float* Wqkv  = (const float*)d_in[6];
    const float* Wproj = (const float*)d_in[7];
    const float* bproj = (const float*)d_in[8];
    const float* W1    = (const float*)d_in[9];
    const float* b1    = (const float*)d_in[10];
    const float* W2    = (const float*)d_in[11];
    const float* b2    = (const float*)d_in[12];
    float* outp = (float*)d_out;

    char* ws = (char*)d_ws;
    size_t off = 0;
    auto take = [&](size_t bytes) -> void* {
        void* p = ws + off;
        off += (bytes + 255) & ~(size_t)255;
        return p;
    };
    u16*   WqkvT  = (u16*)take((size_t)2304 * 768 * 2);
    u16*   WprojT = (u16*)take((size_t)768 * 768 * 2);
    u16*   W1T    = (u16*)take((size_t)3072 * 768 * 2);
    u16*   W2T    = (u16*)take((size_t)768 * 3072 * 2);
    float* probs  = (float*)take((size_t)32 * 2048 * 4);
    int*   idxb   = (int*)take((size_t)32 * 512 * 4);
    float* gateb  = (float*)take((size_t)32 * 512 * 4);
    int*   revb   = (int*)take((size_t)8 * 2048 * 4 * 4);
    u16*   xn     = (u16*)take((size_t)8 * 2048 * 768 * 2);
    u16*   qkvb   = (u16*)take((size_t)32 * 512 * 1536 * 2);  // aliased as h-pool in MLP phase
    u16*   vtb    = (u16*)take((size_t)32 * 768 * 512 * 2);
    u16*   ob     = (u16*)take((size_t)32 * 512 * 768 * 2);
    u16*   yeb    = (u16*)take((size_t)32 * 512 * 768 * 2);
    u16*   hb     = qkvb;

    const int Dk_[4] = {768, 384, 192, 96};
    const int He_[4] = {3072, 1536, 768, 384};
    size_t eoffH[4];
    { size_t s = 0; for (int e = 0; e < 4; e++) { eoffH[e] = s; s += (size_t)8 * 512 * He_[e]; } }

    // --- weight transposes (one launch) ---
    WtJobs wj{};
    wj.src[0] = Wqkv;  wj.dst[0] = WqkvT;  wj.K[0] = 768;  wj.N[0] = 2304;
    wj.src[1] = Wproj; wj.dst[1] = WprojT; wj.K[1] = 768;  wj.N[1] = 768;
    wj.src[2] = W1;    wj.dst[2] = W1T;    wj.K[2] = 768;  wj.N[2] = 3072;
    wj.src[3] = W2;    wj.dst[3] = W2T;    wj.K[3] = 3072; wj.N[3] = 768;
    { int s = 0; for (int j = 0; j < 4; j++) { wj.ntx[j] = wj.N[j] / 32; wj.start[j] = s; s += (wj.N[j] / 32) * (wj.K[j] / 32); } wj.start[4] = s;
      wt_all_kernel<<<s, 256, 0, stream>>>(wj); }

    routerln_kernel<<<4096, 256, 0, stream>>>(x, Wr, ln1g, ln1b, probs, xn);
    topk_kernel<<<32, 1024, 0, stream>>>(probs, idxb, gateb, revb);

    // --- qkv (fused experts) ---
    {
        GemmJobs ga{};
        ga.BT = WqkvT; ga.bias = nullptr; ga.ldb = 768;
        int s = 0;
        for (int e = 0; e < 4; e++) {
            int tps = (Dk_[e] + 127) / 128;
            ga.A[e] = xn; ga.C[e] = qkvb + (size_t)e * 512 * 1536; ga.VT[e] = vtb + (size_t)e * 768 * 512;
            ga.idx[e] = idxb + e * 512;
            ga.sAb[e] = (long)2048 * 768; ga.sCb[e] = (long)4 * 512 * 1536; ga.sVb[e] = (long)4 * 768 * 512;
            ga.lda[e] = 768; ga.ldc[e] = 1536; ga.nk[e] = Dk_[e] / 32; ga.nmask[e] = Dk_[e];
            ga.tps[e] = tps; ga.tstart[e] = s; s += 3 * tps;
        }
        gemm_kernel<0><<<s * 32, 256, 0, stream>>>(ga);
    }

    attn_kernel<<<736, 512, 0, stream>>>(qkvb, vtb, ob);

    // --- proj (fused experts) ---
    {
        GemmJobs ga{};
        ga.BT = WprojT; ga.bias = bproj; ga.ldb = 768;
        int s = 0;
        for (int e = 0; e < 4; e++) {
            int tps = (Dk_[e] + 127) / 128;
            ga.A[e] = ob + (size_t)e * 512 * 768; ga.C[e] = yeb + (size_t)e * 512 * 768;
            ga.VT[e] = nullptr; ga.idx[e] = nullptr;
            ga.sAb[e] = (long)4 * 512 * 768; ga.sCb[e] = (long)4 * 512 * 768; ga.sVb[e] = 0;
            ga.lda[e] = 768; ga.ldc[e] = 768; ga.nk[e] = Dk_[e] / 32; ga.nmask[e] = 768;
            ga.tps[e] = tps; ga.tstart[e] = s; s += tps;
        }
        gemm_kernel<1><<<s * 32, 256, 0, stream>>>(ga);
    }

    combineln_kernel<1><<<4096, 256, 0, stream>>>(x, outp, yeb, revb, gateb, ln2g, ln2b, xn);

    // --- mlp1 (fused experts) ---
    {
        GemmJobs ga{};
        ga.BT = W1T; ga.bias = b1; ga.ldb = 768;
        int s = 0;
        for (int e = 0; e < 4; e++) {
            ga.A[e] = xn; ga.C[e] = hb + eoffH[e]; ga.VT[e] = nullptr; ga.idx[e] = idxb + e * 512;
            ga.sAb[e] = (long)2048 * 768; ga.sCb[e] = (long)512 * He_[e]; ga.sVb[e] = 0;
            ga.lda[e] = 768; ga.ldc[e] = He_[e]; ga.nk[e] = Dk_[e] / 32; ga.nmask[e] = He_[e];
            ga.tps[e] = He_[e] / 128; ga.tstart[e] = s; s += He_[e] / 128;
        }
        gemm_kernel<2><<<s * 32, 256, 0, stream>>>(ga);
    }
    // --- mlp2 (fused experts) ---
    {
        GemmJobs ga{};
        ga.BT = W2T; ga.bias = b2; ga.ldb = 3072;
        int s = 0;
        for (int e = 0; e < 4; e++) {
            int tps = (Dk_[e] + 127) / 128;
            ga.A[e] = hb + eoffH[e]; ga.C[e] = yeb + (size_t)e * 512 * 768;
            ga.VT[e] = nullptr; ga.idx[e] = nullptr;
            ga.sAb[e] = (long)512 * He_[e]; ga.sCb[e] = (long)4 * 512 * 768; ga.sVb[e] = 0;
            ga.lda[e] = He_[e]; ga.ldc[e] = 768; ga.nk[e] = He_[e] / 32; ga.nmask[e] = 768;
            ga.tps[e] = tps; ga.tstart[e] = s; s += tps;
        }
        gemm_kernel<1><<<s * 32, 256, 0, stream>>>(ga);
    }

    combineln_kernel<0><<<4096, 256, 0, stream>>>(outp, outp, yeb, revb, gateb, nullptr, nullptr, nullptr);
}